// Round 1
// baseline (2154.304 us; speedup 1.0000x reference)
//
#include <hip/hip_runtime.h>
#include <math.h>

#define N 2048
#define DIM 128
#define CAP (N*64)
#define LOGN 7.6246189861593985f

typedef unsigned long long u64;

// ---------------------------------------------------------------- precompute

__global__ __launch_bounds__(256) void k_init(double* k1acc, double* smfs) {
  if (threadIdx.x == 0) { *k1acc = 0.0; *smfs = 0.0; }
}

// inter = exp(-(A @ B^T)), accumulate k1 = sum(inter)
__global__ __launch_bounds__(256) void k_gemm_inter(
    const float* __restrict__ A, const float* __restrict__ B,
    float* __restrict__ O, double* __restrict__ k1acc) {
  __shared__ __align__(16) float As[64][65];
  __shared__ __align__(16) float Bs[64][65];
  __shared__ float red[256];
  const int t = threadIdx.x;
  const int i0 = blockIdx.y * 64, j0 = blockIdx.x * 64;
  const int tx = t & 15, ty = t >> 4;
  float acc[4][4] = {};
  for (int kk = 0; kk < DIM; kk += 64) {
    if (kk) __syncthreads();
    for (int q = t; q < 64 * 16; q += 256) {
      int row = q >> 4, k4 = (q & 15) << 2;
      float4 av = *(const float4*)&A[(size_t)(i0 + row) * DIM + kk + k4];
      As[k4 + 0][row] = av.x; As[k4 + 1][row] = av.y;
      As[k4 + 2][row] = av.z; As[k4 + 3][row] = av.w;
      float4 bv = *(const float4*)&B[(size_t)(j0 + row) * DIM + kk + k4];
      Bs[k4 + 0][row] = bv.x; Bs[k4 + 1][row] = bv.y;
      Bs[k4 + 2][row] = bv.z; Bs[k4 + 3][row] = bv.w;
    }
    __syncthreads();
    #pragma unroll 4
    for (int k = 0; k < 64; ++k) {
      float av[4], bv[4];
      #pragma unroll
      for (int d = 0; d < 4; ++d) { av[d] = As[k][ty * 4 + d]; bv[d] = Bs[k][tx * 4 + d]; }
      #pragma unroll
      for (int di = 0; di < 4; ++di)
        #pragma unroll
        for (int dj = 0; dj < 4; ++dj)
          acc[di][dj] = fmaf(av[di], bv[dj], acc[di][dj]);
    }
  }
  float psum = 0.f;
  #pragma unroll
  for (int di = 0; di < 4; ++di)
    #pragma unroll
    for (int dj = 0; dj < 4; ++dj) {
      float vv = __expf(-acc[di][dj]);
      O[(size_t)(i0 + ty * 4 + di) * N + (j0 + tx * 4 + dj)] = vv;
      psum += vv;
    }
  red[t] = psum; __syncthreads();
  for (int off = 128; off; off >>= 1) { if (t < off) red[t] += red[t + off]; __syncthreads(); }
  if (t == 0) atomicAdd(k1acc, (double)red[0]);
}

__global__ __launch_bounds__(256) void k_count(const float* __restrict__ adj, int* __restrict__ cnt) {
  int i = blockIdx.x * 4 + (threadIdx.x >> 6);
  int lane = threadIdx.x & 63;
  const float* row = adj + (size_t)i * N;
  int c = 0;
  for (int j = lane; j < N; j += 64) c += (row[j] != 0.f) ? 1 : 0;
  for (int off = 32; off; off >>= 1) c += __shfl_down(c, off);
  if (lane == 0) cnt[i] = c;
}

__global__ __launch_bounds__(256) void k_scan(const int* __restrict__ cnt, int* __restrict__ rp) {
  __shared__ int sums[256];
  int t = threadIdx.x;
  int local[8]; int run = 0;
  int base = t * 8;
  #pragma unroll
  for (int k = 0; k < 8; ++k) { local[k] = run; run += cnt[base + k]; }
  sums[t] = run; __syncthreads();
  for (int off = 1; off < 256; off <<= 1) {
    int val = (t >= off) ? sums[t - off] : 0;
    __syncthreads();
    sums[t] += val;
    __syncthreads();
  }
  int pre = (t == 0) ? 0 : sums[t - 1];
  #pragma unroll
  for (int k = 0; k < 8; ++k) rp[base + k] = pre + local[k];
  if (t == 255) rp[N] = sums[255];
}

__global__ __launch_bounds__(256) void k_fill(const float* __restrict__ adj, const int* __restrict__ rp,
                                              int* __restrict__ cols, int* __restrict__ rows) {
  int i = blockIdx.x * 4 + (threadIdx.x >> 6);
  int lane = threadIdx.x & 63;
  const float* row = adj + (size_t)i * N;
  int pos = rp[i];
  for (int j0 = 0; j0 < N; j0 += 64) {
    bool p = row[j0 + lane] != 0.f;
    u64 mask = __ballot(p);
    if (p) {
      int off = __popcll(mask & ((1ull << lane) - 1ull));
      cols[pos + off] = j0 + lane;
      rows[pos + off] = i;
    }
    pos += __popcll(mask);
  }
}

// vals[p] = exp(-dot(emb[rows[p]], emb[cols[p]]))
__global__ __launch_bounds__(256) void k_vals(const int* __restrict__ rp, const int* __restrict__ rows,
                                              const int* __restrict__ cols, float* __restrict__ vals,
                                              const float* __restrict__ emb) {
  int p = blockIdx.x * 4 + (threadIdx.x >> 6);
  int lane = threadIdx.x & 63;
  int total = rp[N];
  if (p >= total) return;
  int i = rows[p], k = cols[p];
  const float* ei = emb + (size_t)i * DIM;
  const float* ek = emb + (size_t)k * DIM;
  float s = ei[lane] * ek[lane] + ei[lane + 64] * ek[lane + 64];
  for (int off = 32; off; off >>= 1) s += __shfl_down(s, off);
  if (lane == 0) vals[p] = __expf(-s);
}

__global__ __launch_bounds__(256) void k_rowstats(const int* __restrict__ rp, const float* __restrict__ vals,
                                                  float* __restrict__ rs, float* __restrict__ rsq) {
  int i = blockIdx.x * 4 + (threadIdx.x >> 6);
  int lane = threadIdx.x & 63;
  int p0 = rp[i], p1 = rp[i + 1];
  float s1 = 0.f, s2 = 0.f;
  for (int p = p0 + lane; p < p1; p += 64) { float w = vals[p]; s1 += w; s2 += w * w; }
  for (int off = 32; off; off >>= 1) { s1 += __shfl_down(s1, off); s2 += __shfl_down(s2, off); }
  if (lane == 0) { rs[i] = s1; rsq[i] = s2; }
}

// ---------------------------------------------------------------- per-iter

// T[i,:] = sum_p vals[p] * S[cols[p], :]
__global__ __launch_bounds__(256) void k_spmm(const int* __restrict__ rp, const int* __restrict__ cols,
                                              const float* __restrict__ vals, const float* __restrict__ S,
                                              float* __restrict__ T) {
  int i = blockIdx.x;
  int j = (blockIdx.y * 256 + threadIdx.x) * 4;
  int p0 = rp[i], p1 = rp[i + 1];
  float4 acc = {0.f, 0.f, 0.f, 0.f};
  for (int p = p0; p < p1; ++p) {
    int k = cols[p]; float w = vals[p];
    float4 sv = *(const float4*)&S[(size_t)k * N + j];
    acc.x = fmaf(w, sv.x, acc.x);
    acc.y = fmaf(w, sv.y, acc.y);
    acc.z = fmaf(w, sv.z, acc.z);
    acc.w = fmaf(w, sv.w, acc.w);
  }
  *(float4*)&T[(size_t)i * N + j] = acc;
}

__global__ __launch_bounds__(256) void k_transpose(const float* __restrict__ in, float* __restrict__ out) {
  __shared__ float tile[32][33];
  int tx = threadIdx.x & 31, ty = threadIdx.x >> 5;
  int bx = blockIdx.x * 32, by = blockIdx.y * 32;
  #pragma unroll
  for (int r = 0; r < 4; ++r) tile[ty + 8 * r][tx] = in[(size_t)(by + ty + 8 * r) * N + bx + tx];
  __syncthreads();
  #pragma unroll
  for (int r = 0; r < 4; ++r) out[(size_t)(bx + ty + 8 * r) * N + by + tx] = tile[tx][ty + 8 * r];
}

// mode 0: t==0 analytic (s uniform);  mode 1: general K-prep;  mode 2: final raw pa/pb
__global__ __launch_bounds__(256) void k_prep(
    int mode,
    const int* __restrict__ rp1, const int* __restrict__ cols1, const float* __restrict__ vals1,
    const int* __restrict__ rp2, const int* __restrict__ cols2, const float* __restrict__ vals2,
    const float* __restrict__ r1sq, const float* __restrict__ rs1,
    const float* __restrict__ r2sq, const float* __restrict__ rs2,
    const float* __restrict__ as_, const float* __restrict__ bs_,
    const float* __restrict__ lamp,
    float* __restrict__ Ai, float* __restrict__ Bj, float* __restrict__ RLi,
    float* __restrict__ v) {
  int g = blockIdx.x * 256 + threadIdx.x;
  float lam = *lamp;
  if (mode == 0) {
    float f = 0.00048828125f - lam * 2048.f;            // 2^-11 - N*lam
    if (g < N) {
      Ai[g] = -2000.f * r1sq[g] * f;
      RLi[g] = 4000.f * rs1[g] * (2.384185791015625e-07f - lam);  // 4000*rs1*(s0 - lam)
    } else if (g < 2 * N) {
      int j = g - N;
      Bj[j] = -2000.f * r2sq[j] * f;
    } else if (g < 3 * N) {
      v[g - 2 * N] = 0.f;
    }
  } else if (mode == 1) {
    if (g < N) {
      int p0 = rp1[g], p1 = rp1[g + 1];
      float acc = 0.f;
      for (int p = p0; p < p1; ++p) { float w = vals1[p]; acc = fmaf(w * w, as_[cols1[p]], acc); }
      Ai[g] = -2000.f * (acc - lam * 2048.f * r1sq[g]);
      RLi[g] = -4000.f * lam * rs1[g];
    } else if (g < 2 * N) {
      int j = g - N;
      int p0 = rp2[j], p1 = rp2[j + 1];
      float acc = 0.f;
      for (int p = p0; p < p1; ++p) { float w = vals2[p]; acc = fmaf(w * w, bs_[cols2[p]], acc); }
      Bj[j] = -2000.f * (acc - lam * 2048.f * r2sq[j]);
    } else if (g < 3 * N) {
      v[g - 2 * N] = 0.f;
    }
  } else {
    if (g < N) {
      int p0 = rp1[g], p1 = rp1[g + 1];
      float acc = 0.f;
      for (int p = p0; p < p1; ++p) { float w = vals1[p]; acc = fmaf(w * w, as_[cols1[p]], acc); }
      Ai[g] = acc;                                      // paf
    } else if (g < 2 * N) {
      int j = g - N;
      int p0 = rp2[j], p1 = rp2[j + 1];
      float acc = 0.f;
      for (int p = p0; p < p1; ++p) { float w = vals2[p]; acc = fmaf(w * w, bs_[cols2[p]], acc); }
      Bj[j] = acc;                                      // pbf
    }
  }
}

// K[i,j] = -100*inter + Ai[i] + Bj[j] + RLi[i]*rs2[j] (+ 4000*Mt[j,i] if hasM)
__global__ __launch_bounds__(256) void k_kbuild(
    const float* __restrict__ inter, const float* __restrict__ Mt,
    const float* __restrict__ Ai, const float* __restrict__ Bj,
    const float* __restrict__ RLi, const float* __restrict__ rs2,
    float* __restrict__ K, int hasM) {
  __shared__ float mt[64][65];
  __shared__ float bjs[64], r2s[64];
  int t = threadIdx.x;
  int i0 = blockIdx.y * 64, j0 = blockIdx.x * 64;
  int c = t & 63, r0 = t >> 6;
  if (hasM) {
    for (int r = r0; r < 64; r += 4) mt[r][c] = Mt[(size_t)(j0 + r) * N + i0 + c];
  }
  if (t < 64) { bjs[t] = Bj[j0 + t]; r2s[t] = rs2[j0 + t]; }
  __syncthreads();
  int jj = c;
  #pragma unroll 4
  for (int rr = 0; rr < 16; ++rr) {
    int ii = r0 + 4 * rr;
    int i = i0 + ii, j = j0 + jj;
    float kv = -100.f * inter[(size_t)i * N + j] + Ai[i] + bjs[jj] + RLi[i] * r2s[jj];
    if (hasM) kv += 4000.f * mt[jj][ii];
    K[(size_t)i * N + j] = kv;
  }
}

__global__ __launch_bounds__(256) void k_rowlse(const float* __restrict__ K, const float* __restrict__ v,
                                                float* __restrict__ u) {
  __shared__ __align__(16) float vs[N];
  int t = threadIdx.x;
  for (int j = t * 4; j < N; j += 1024) *(float4*)&vs[j] = *(const float4*)&v[j];
  __syncthreads();
  int lane = t & 63;
  int i = blockIdx.x * 4 + (t >> 6);
  const float* Kr = K + (size_t)i * N;
  float m[4] = {-INFINITY, -INFINITY, -INFINITY, -INFINITY};
  float s[4] = {0.f, 0.f, 0.f, 0.f};
  for (int j = lane * 4; j < N; j += 256) {
    float4 kv = *(const float4*)&Kr[j];
    float x[4] = {kv.x + vs[j], kv.y + vs[j + 1], kv.z + vs[j + 2], kv.w + vs[j + 3]};
    #pragma unroll
    for (int q = 0; q < 4; ++q) {
      float nm = fmaxf(m[q], x[q]);
      s[q] = s[q] * __expf(m[q] - nm) + __expf(x[q] - nm);
      m[q] = nm;
    }
  }
  #pragma unroll
  for (int q = 1; q < 4; ++q) {
    float nm = fmaxf(m[0], m[q]);
    s[0] = s[0] * __expf(m[0] - nm) + s[q] * __expf(m[q] - nm);
    m[0] = nm;
  }
  float mm = m[0], ss = s[0];
  for (int off = 32; off; off >>= 1) {
    float mo = __shfl_xor(mm, off);
    float so = __shfl_xor(ss, off);
    float nm = fmaxf(mm, mo);
    ss = ss * __expf(mm - nm) + so * __expf(mo - nm);
    mm = nm;
  }
  if (lane == 0) u[i] = -LOGN - (mm + __logf(ss));
}

__global__ __launch_bounds__(256) void k_collse_part(const float* __restrict__ K, const float* __restrict__ u,
                                                     float* __restrict__ pm, float* __restrict__ ps) {
  __shared__ float us[64];
  int t = threadIdx.x;
  int c = blockIdx.x * 256 + t;
  int r0 = blockIdx.y * 64;
  if (t < 64) us[t] = u[r0 + t];
  __syncthreads();
  float m = -INFINITY, s = 0.f;
  const float* Kp = K + (size_t)r0 * N + c;
  #pragma unroll 4
  for (int r = 0; r < 64; ++r) {
    float x = Kp[(size_t)r * N] + us[r];
    float nm = fmaxf(m, x);
    s = s * __expf(m - nm) + __expf(x - nm);
    m = nm;
  }
  pm[blockIdx.y * N + c] = m;
  ps[blockIdx.y * N + c] = s;
}

__global__ __launch_bounds__(256) void k_collse_comb(const float* __restrict__ pm, const float* __restrict__ ps,
                                                     float* __restrict__ v) {
  int c = blockIdx.x * 256 + threadIdx.x;
  float m = -INFINITY, s = 0.f;
  #pragma unroll 4
  for (int k = 0; k < 32; ++k) {
    float mo = pm[k * N + c], so = ps[k * N + c];
    float nm = fmaxf(m, mo);
    s = s * __expf(m - nm) + so * __expf(mo - nm);
    m = nm;
  }
  v[c] = -LOGN - (m + __logf(s));
}

// s = exp(K + u + v); also rowsums -> as_, per-block column partials -> bsp
__global__ __launch_bounds__(256) void k_swrite(const float* __restrict__ K, const float* __restrict__ u,
                                                const float* __restrict__ v, float* __restrict__ s,
                                                float* __restrict__ as_, float* __restrict__ bsp) {
  __shared__ __align__(16) float vs[N];
  __shared__ __align__(16) float bc[N];
  int t = threadIdx.x;
  for (int j = t * 4; j < N; j += 1024) *(float4*)&vs[j] = *(const float4*)&v[j];
  __syncthreads();
  int lane = t & 63, w = t >> 6;
  float4 cacc[8];
  #pragma unroll
  for (int q = 0; q < 8; ++q) cacc[q] = make_float4(0.f, 0.f, 0.f, 0.f);
  int ibase = blockIdx.x * 8 + w * 2;
  for (int rr = 0; rr < 2; ++rr) {
    int i = ibase + rr;
    float ui = u[i];
    const float* Kr = K + (size_t)i * N;
    float* sr = s + (size_t)i * N;
    float rsum = 0.f;
    #pragma unroll
    for (int q = 0; q < 8; ++q) {
      int j = lane * 4 + q * 256;
      float4 kv = *(const float4*)&Kr[j];
      float4 sv;
      sv.x = __expf(kv.x + ui + vs[j]);
      sv.y = __expf(kv.y + ui + vs[j + 1]);
      sv.z = __expf(kv.z + ui + vs[j + 2]);
      sv.w = __expf(kv.w + ui + vs[j + 3]);
      *(float4*)&sr[j] = sv;
      rsum += sv.x + sv.y + sv.z + sv.w;
      cacc[q].x += sv.x; cacc[q].y += sv.y; cacc[q].z += sv.z; cacc[q].w += sv.w;
    }
    for (int off = 32; off; off >>= 1) rsum += __shfl_down(rsum, off);
    if (lane == 0) as_[i] = rsum;
  }
  for (int ww = 0; ww < 4; ++ww) {
    if (w == ww) {
      #pragma unroll
      for (int q = 0; q < 8; ++q) {
        int j = lane * 4 + q * 256;
        if (ww == 0) *(float4*)&bc[j] = cacc[q];
        else {
          float4 old = *(float4*)&bc[j];
          old.x += cacc[q].x; old.y += cacc[q].y; old.z += cacc[q].z; old.w += cacc[q].w;
          *(float4*)&bc[j] = old;
        }
      }
    }
    __syncthreads();
  }
  float* bout = bsp + (size_t)blockIdx.x * N;
  for (int j = t * 4; j < N; j += 1024) *(float4*)&bout[j] = *(const float4*)&bc[j];
}

__global__ __launch_bounds__(256) void k_bscomb(const float* __restrict__ bsp, float* __restrict__ bs_) {
  int c = blockIdx.x * 256 + threadIdx.x;
  float acc = 0.f;
  for (int b = 0; b < 256; ++b) acc += bsp[(size_t)b * N + c];
  bs_[c] = acc;
}

// ---------------------------------------------------------------- final

__global__ __launch_bounds__(256) void k_rowdots(const float* __restrict__ inter, const float* __restrict__ s,
                                                 const float* __restrict__ rs2, float* __restrict__ sisr,
                                                 float* __restrict__ yv) {
  __shared__ __align__(16) float r2[N];
  int t = threadIdx.x;
  for (int j = t * 4; j < N; j += 1024) *(float4*)&r2[j] = *(const float4*)&rs2[j];
  __syncthreads();
  int lane = t & 63;
  int i = blockIdx.x * 4 + (t >> 6);
  const float* ir = inter + (size_t)i * N;
  const float* sr = s + (size_t)i * N;
  float d1 = 0.f, d2 = 0.f;
  for (int j = lane * 4; j < N; j += 256) {
    float4 iv = *(const float4*)&ir[j];
    float4 sv = *(const float4*)&sr[j];
    d1 += iv.x * sv.x + iv.y * sv.y + iv.z * sv.z + iv.w * sv.w;
    d2 += sv.x * r2[j] + sv.y * r2[j + 1] + sv.z * r2[j + 2] + sv.w * r2[j + 3];
  }
  for (int off = 32; off; off >>= 1) { d1 += __shfl_down(d1, off); d2 += __shfl_down(d2, off); }
  if (lane == 0) { sisr[i] = d1; yv[i] = d2; }
}

__global__ __launch_bounds__(256) void k_mts(const float* __restrict__ Mt, const float* __restrict__ s,
                                             double* __restrict__ smfs) {
  __shared__ float mt[64][65];
  __shared__ float red[256];
  int t = threadIdx.x;
  int i0 = blockIdx.y * 64, j0 = blockIdx.x * 64;
  int c = t & 63, r0 = t >> 6;
  for (int r = r0; r < 64; r += 4) mt[r][c] = Mt[(size_t)(j0 + r) * N + i0 + c];
  __syncthreads();
  float acc = 0.f;
  int jj = c;
  #pragma unroll 4
  for (int rr = 0; rr < 16; ++rr) {
    int ii = r0 + 4 * rr;
    acc = fmaf(s[(size_t)(i0 + ii) * N + j0 + jj], mt[jj][ii], acc);
  }
  red[t] = acc; __syncthreads();
  for (int off = 128; off; off >>= 1) { if (t < off) red[t] += red[t + off]; __syncthreads(); }
  if (t == 0) atomicAdd(smfs, (double)red[0]);
}

__global__ __launch_bounds__(256) void k_final(
    const float* __restrict__ paf, const float* __restrict__ pbf,
    const float* __restrict__ r1sq, const float* __restrict__ r2sq,
    const float* __restrict__ rs1, const float* __restrict__ rs2,
    const float* __restrict__ as_, const float* __restrict__ bs_,
    const float* __restrict__ yv, const float* __restrict__ sisr,
    const double* __restrict__ k1p, const double* __restrict__ smfsp,
    const float* __restrict__ lamp, float* __restrict__ out_loss, float* __restrict__ out_lam) {
  __shared__ double red[256];
  int t = threadIdx.x;
  auto dotv = [&](const float* a, const float* b) -> double {
    double acc = 0.0;
    for (int k = t; k < N; k += 256) acc += (double)a[k] * (b ? (double)b[k] : 1.0);
    red[t] = acc; __syncthreads();
    for (int off = 128; off; off >>= 1) { if (t < off) red[t] += red[t + off]; __syncthreads(); }
    double r = red[0]; __syncthreads();
    return r;
  };
  double paas = dotv(paf, as_);
  double pbbs = dotv(pbf, bs_);
  double r1as = dotv(r1sq, as_);
  double c2bs = dotv(r2sq, bs_);
  double rs1y = dotv(rs1, yv);
  double sis  = dotv(sisr, nullptr);
  double sr1  = dotv(r1sq, nullptr);
  double sr2  = dotv(r2sq, nullptr);
  double ss1  = dotv(rs1, nullptr);
  double ss2  = dotv(rs2, nullptr);
  if (t == 0) {
    double k1 = *k1p, smfs = *smfsp;
    double lam0 = (double)*lamp;
    double k2 = 2048.0 * r1as + 2048.0 * c2bs - 2.0 * rs1y;
    double k3 = 2048.0 * 2048.0 * (sr1 + sr2) - 2.0 * ss1 * ss2;
    double upd = (k1 + 40.0 * k2) / (40.0 * k3);
    double lamn = 0.01 * upd + 0.99 * lam0;
    double g1 = paas + pbbs - 2.0 * smfs;
    double wl = sis - lamn * k1;
    double gwl = g1 - 2.0 * lamn * k2 + lamn * lamn * k3;
    double loss = wl + 20.0 * gwl + 20.0;
    *out_loss = (float)loss;
    *out_lam = (float)lamn;
  }
}

__global__ __launch_bounds__(256) void k_copys(const float* __restrict__ s, float* __restrict__ out) {
  size_t base = ((size_t)blockIdx.x * 256 + threadIdx.x) * 4;
  if (base < (size_t)N * N) {
    float4 v = *(const float4*)&s[base];
    out[base + 0] = v.x; out[base + 1] = v.y; out[base + 2] = v.z; out[base + 3] = v.w;
  }
}

// ---------------------------------------------------------------- launch

extern "C" void kernel_launch(void* const* d_in, const int* in_sizes, int n_in,
                              void* d_out, int out_size, void* d_ws, size_t ws_size,
                              hipStream_t stream) {
  (void)in_sizes; (void)n_in; (void)out_size; (void)ws_size;
  const float* out1 = (const float*)d_in[0];
  const float* out2 = (const float*)d_in[1];
  const float* adj1 = (const float*)d_in[2];
  const float* adj2 = (const float*)d_in[3];
  const float* lamp = (const float*)d_in[4];
  float* o = (float*)d_out;

  char* w = (char*)d_ws;
  size_t off = 0;
  auto alloc = [&](size_t bytes) -> void* {
    void* p = w + off;
    off = (off + bytes + 255) & ~(size_t)255;
    return p;
  };
  const size_t NNf = (size_t)N * N * sizeof(float);
  float* inter = (float*)alloc(NNf);
  float* bufC  = (float*)alloc(NNf);   // T, then Mt
  float* bufD  = (float*)alloc(NNf);   // Tt, then K
  float* sbuf  = (float*)alloc(NNf);
  int* rp1   = (int*)alloc((N + 1) * sizeof(int));
  int* rp2   = (int*)alloc((N + 1) * sizeof(int));
  int* cnt   = (int*)alloc(N * sizeof(int));
  int* cols1 = (int*)alloc(CAP * sizeof(int));
  int* rows1 = (int*)alloc(CAP * sizeof(int));
  int* cols2 = (int*)alloc(CAP * sizeof(int));
  int* rows2 = (int*)alloc(CAP * sizeof(int));
  float* vals1 = (float*)alloc(CAP * sizeof(float));
  float* vals2 = (float*)alloc(CAP * sizeof(float));
  float* r1sq = (float*)alloc(N * sizeof(float));
  float* rs1  = (float*)alloc(N * sizeof(float));
  float* r2sq = (float*)alloc(N * sizeof(float));
  float* rs2v = (float*)alloc(N * sizeof(float));
  float* asv  = (float*)alloc(N * sizeof(float));
  float* bsv  = (float*)alloc(N * sizeof(float));
  float* uv   = (float*)alloc(N * sizeof(float));
  float* vv   = (float*)alloc(N * sizeof(float));
  float* Ai   = (float*)alloc(N * sizeof(float));
  float* Bj   = (float*)alloc(N * sizeof(float));
  float* RLi  = (float*)alloc(N * sizeof(float));
  float* yv   = (float*)alloc(N * sizeof(float));
  float* sisr = (float*)alloc(N * sizeof(float));
  float* pm   = (float*)alloc(32 * N * sizeof(float));
  float* ps   = (float*)alloc(32 * N * sizeof(float));
  float* bsp  = (float*)alloc(256 * N * sizeof(float));
  double* k1acc = (double*)alloc(sizeof(double));
  double* smfs  = (double*)alloc(sizeof(double));

  dim3 b(256);

  // ---- precompute
  k_init<<<1, b, 0, stream>>>(k1acc, smfs);
  k_gemm_inter<<<dim3(32, 32), b, 0, stream>>>(out1, out2, inter, k1acc);
  k_count<<<512, b, 0, stream>>>(adj1, cnt);
  k_scan<<<1, b, 0, stream>>>(cnt, rp1);
  k_count<<<512, b, 0, stream>>>(adj2, cnt);
  k_scan<<<1, b, 0, stream>>>(cnt, rp2);
  k_fill<<<512, b, 0, stream>>>(adj1, rp1, cols1, rows1);
  k_fill<<<512, b, 0, stream>>>(adj2, rp2, cols2, rows2);
  k_vals<<<CAP / 4, b, 0, stream>>>(rp1, rows1, cols1, vals1, out1);
  k_vals<<<CAP / 4, b, 0, stream>>>(rp2, rows2, cols2, vals2, out2);
  k_rowstats<<<512, b, 0, stream>>>(rp1, vals1, rs1, r1sq);
  k_rowstats<<<512, b, 0, stream>>>(rp2, vals2, rs2v, r2sq);

  // ---- outer loop
  for (int t = 0; t < 10; ++t) {
    if (t > 0) {
      k_spmm<<<dim3(N, 2), b, 0, stream>>>(rp1, cols1, vals1, sbuf, bufC);
      k_transpose<<<dim3(64, 64), b, 0, stream>>>(bufC, bufD);
      k_spmm<<<dim3(N, 2), b, 0, stream>>>(rp2, cols2, vals2, bufD, bufC);
    }
    k_prep<<<24, b, 0, stream>>>((t == 0) ? 0 : 1, rp1, cols1, vals1, rp2, cols2, vals2,
                                 r1sq, rs1, r2sq, rs2v, asv, bsv, lamp, Ai, Bj, RLi, vv);
    k_kbuild<<<dim3(32, 32), b, 0, stream>>>(inter, bufC, Ai, Bj, RLi, rs2v, bufD, (t > 0) ? 1 : 0);
    for (int r = 0; r < 5; ++r) {
      k_rowlse<<<512, b, 0, stream>>>(bufD, vv, uv);
      k_collse_part<<<dim3(8, 32), b, 0, stream>>>(bufD, uv, pm, ps);
      k_collse_comb<<<8, b, 0, stream>>>(pm, ps, vv);
    }
    k_swrite<<<256, b, 0, stream>>>(bufD, uv, vv, sbuf, asv, bsp);
    k_bscomb<<<8, b, 0, stream>>>(bsp, bsv);
  }

  // ---- final: lambda update + loss
  k_spmm<<<dim3(N, 2), b, 0, stream>>>(rp1, cols1, vals1, sbuf, bufC);
  k_transpose<<<dim3(64, 64), b, 0, stream>>>(bufC, bufD);
  k_spmm<<<dim3(N, 2), b, 0, stream>>>(rp2, cols2, vals2, bufD, bufC);
  k_prep<<<24, b, 0, stream>>>(2, rp1, cols1, vals1, rp2, cols2, vals2,
                               r1sq, rs1, r2sq, rs2v, asv, bsv, lamp, Ai, Bj, RLi, vv);
  k_rowdots<<<512, b, 0, stream>>>(inter, sbuf, rs2v, sisr, yv);
  k_mts<<<dim3(32, 32), b, 0, stream>>>(bufC, sbuf, smfs);
  k_final<<<1, b, 0, stream>>>(Ai, Bj, r1sq, r2sq, rs1, rs2v, asv, bsv, yv, sisr,
                               k1acc, smfs, lamp, o, o + 1 + (size_t)N * N);
  k_copys<<<4096, b, 0, stream>>>(sbuf, o + 1);
}